// Round 6
// baseline (625.348 us; speedup 1.0000x reference)
//
#include <hip/hip_runtime.h>
#include <hip/hip_bf16.h>

// N=32768 queries, D=256 dims, K=4096 codes (fp32 in/out).
#define VQ_N 32768
#define VQ_D 256
#define VQ_K 4096
#define BAND 16.0f                 // >= 2 * worst-case bf16 score error (~3.7)
#define QCAP (2u * 1024u * 1024u)  // global queue capacity (u32 entries)
#define BUFCAP 2048                // per-block LDS queue buffer

typedef __attribute__((ext_vector_type(8))) short short8;  // 8 bf16 (4 VGPRs)
typedef __attribute__((ext_vector_type(4))) float f32x4;   // MFMA C/D frag

// monotone float<->uint map (total order incl. negatives)
__device__ __forceinline__ unsigned fmap(float f) {
    unsigned b = __float_as_uint(f);
    return (b & 0x80000000u) ? ~b : (b | 0x80000000u);
}
__device__ __forceinline__ float fmapinv(unsigned u) {
    unsigned b = (u & 0x80000000u) ? (u & 0x7FFFFFFFu) : ~u;
    return __uint_as_float(b);
}

// async global->LDS: global src is PER-LANE, LDS dest is wave-uniform base,
// HW writes base + lane*16.
__device__ __forceinline__ void async16(const void* g, void* l) {
    __builtin_amdgcn_global_load_lds(
        (const __attribute__((address_space(1))) unsigned int*)g,
        (__attribute__((address_space(3))) unsigned int*)l, 16, 0, 0);
}

__device__ __forceinline__ short8 pack8(float4 a, float4 b) {
    union { __hip_bfloat16 h[8]; short8 s8; } u;
    u.h[0] = __float2bfloat16(a.x); u.h[1] = __float2bfloat16(a.y);
    u.h[2] = __float2bfloat16(a.z); u.h[3] = __float2bfloat16(a.w);
    u.h[4] = __float2bfloat16(b.x); u.h[5] = __float2bfloat16(b.y);
    u.h[6] = __float2bfloat16(b.z); u.h[7] = __float2bfloat16(b.w);
    return u.s8;
}

// ---------------------------------------------------------------------------
// prep_all: one fused kernel (replaces 2 preps + c2 + 3 memsets).
//  blocks [0,2048):    xb_sw  — bf16 x in A-swizzled slot order
//                      slot s of row holds k-quad q = s ^ (row&15)  (8 bf16)
//  blocks [2048,2304): cbb_sw — bf16 -2*cb in B-swizzled order + c2 (fp32)
//                      slot j=ks*4+s of code holds kq = (s - (code>>1))&3
//  blocks [2304,2432): rowmin/keys init
//  block  2432:        qcnt/overflow/loss/done init
// ---------------------------------------------------------------------------
__global__ __launch_bounds__(256)
void prep_all_kernel(const float* __restrict__ x, const float* __restrict__ cb,
                     short8* __restrict__ xb_sw, short8* __restrict__ cbb_sw,
                     float* __restrict__ c2, unsigned int* __restrict__ rowmin,
                     unsigned long long* __restrict__ keys,
                     unsigned int* __restrict__ ctrl /*qcnt,ovf,loss,done*/) {
    const int b = blockIdx.x, t = threadIdx.x;
    if (b < 2048) {                       // ---- xb_sw: 16 rows per block
        #pragma unroll
        for (int h = 0; h < 2; ++h) {
            const int u   = t + h * 256;            // 0..511 slot-units
            const int row = b * 16 + (u >> 5);
            const int s   = u & 31;
            const int q   = s ^ (row & 15);
            const float4 a = reinterpret_cast<const float4*>(x)[(size_t)row * 64 + q * 2];
            const float4 c = reinterpret_cast<const float4*>(x)[(size_t)row * 64 + q * 2 + 1];
            xb_sw[(size_t)row * 32 + s] = pack8(a, c);
        }
    } else if (b < 2304) {                // ---- cbb_sw + c2: 16 codes per block
        const int code = (b - 2048) * 16 + (t >> 4);
        float ss = 0.0f;
        #pragma unroll
        for (int h = 0; h < 2; ++h) {
            const int j  = (t & 15) * 2 + h;        // 0..31
            const int ks = j >> 2, sl = j & 3;
            const int kq = (sl - (code >> 1)) & 3;
            const int k  = ks * 32 + kq * 8;
            const float4 a = reinterpret_cast<const float4*>(cb)[(size_t)code * 64 + k / 4];
            const float4 c = reinterpret_cast<const float4*>(cb)[(size_t)code * 64 + k / 4 + 1];
            ss += a.x*a.x + a.y*a.y + a.z*a.z + a.w*a.w
                + c.x*c.x + c.y*c.y + c.z*c.z + c.w*c.w;
            const float4 na = make_float4(-2.f*a.x, -2.f*a.y, -2.f*a.z, -2.f*a.w);
            const float4 nc = make_float4(-2.f*c.x, -2.f*c.y, -2.f*c.z, -2.f*c.w);
            cbb_sw[(size_t)code * 32 + j] = pack8(na, nc);
        }
        #pragma unroll
        for (int off = 1; off < 16; off <<= 1) ss += __shfl_xor(ss, off, 64);
        if ((t & 15) == 0) c2[code] = ss;
    } else if (b < 2432) {                // ---- rowmin + keys init
        const int i = (b - 2304) * 256 + t;
        rowmin[i] = 0xFFFFFFFFu;
        keys[i]   = ~0ull;
    } else {                              // ---- control words
        if (t < 8) ctrl[t] = 0u;
    }
}

// ---------------------------------------------------------------------------
// A-resident MFMA sweep. Block = 128 rows x 1024 codes (gridDim.y=4 splits).
// A-tile (128x256 bf16, 64KB, swizzled) staged ONCE; B double-buffered
// (256 codes x 32k = 16KB/step). 512 thr = 8 waves (2 row-halves x 4
// code-quarters), each wave a 64x64 tile: acc[4][4], 16 MFMA + 8 ds_read_b128
// per step. Flattened 32 steps (4 ccts x 8 ks), ONE barrier per step,
// stage-issue before compute. MIN epilogue deferred to registers.
// ---------------------------------------------------------------------------
template<bool COLLECT>
__global__ __launch_bounds__(512, 2)
void sweep_kernel(const short8* __restrict__ xb_sw,
                  const short8* __restrict__ cbb_sw,
                  const float* __restrict__ c2,
                  unsigned int* __restrict__ rowmin,
                  unsigned int* __restrict__ qcnt,
                  unsigned int* __restrict__ overflow,
                  unsigned int* __restrict__ queue) {
    __shared__ __attribute__((aligned(16))) char As[128 * 512];      // 64 KB
    __shared__ __attribute__((aligned(16))) char Bs[2][256 * 64];    // 2x16 KB
    __shared__ unsigned int rowmin_s[128];
    __shared__ float        thr_s[128];
    __shared__ unsigned int qbuf[BUFCAP];
    __shared__ int qn_s, qbase_s;

    const int t = threadIdx.x;
    const int lane = t & 63, wave = t >> 6;        // 8 waves
    const int wr = wave >> 2, wc = wave & 3;       // 2x4: 64-row x 64-code tile
    const int fr = lane & 15, kg = lane >> 4;
    const int rowbase = blockIdx.x * 128;
    const int code0   = blockIdx.y * 1024;

    if (COLLECT) {
        if (t < 128) thr_s[t] = fmapinv(rowmin[rowbase + t]) + BAND;
        if (t == 0) qn_s = 0;
    } else {
        if (t < 128) rowmin_s[t] = 0xFFFFFFFFu;
    }

    // ---- stage A once: wave w covers rows [w*16, w*16+16), linear 16B slots
    {
        const char* asrc = (const char*)xb_sw + (size_t)rowbase * 512 + wave * 8192
                           + lane * 16;
        char* adst = As + wave * 8192;
        #pragma unroll
        for (int i = 0; i < 8; ++i)
            async16(asrc + i * 1024, adst + i * 1024);
    }
    // ---- stage B step 0 (cct=0, ks=0) into buf 0
    {
        const int cg0 = code0;                     // + cct*256, cct=0
        #pragma unroll
        for (int i = 0; i < 2; ++i) {
            const int code = cg0 + wave * 32 + i * 16 + (lane >> 2);
            async16((const char*)cbb_sw + (size_t)code * 512 + /*ks*/0 * 64
                        + (lane & 3) * 16,
                    Bs[0] + wave * 2048 + i * 1024);
        }
    }
    __syncthreads();                               // drains A + B0

    float runv[4][4];
    #pragma unroll
    for (int m = 0; m < 4; ++m)
        #pragma unroll
        for (int r = 0; r < 4; ++r) runv[m][r] = 3.4e38f;

    f32x4 acc[4][4];
    #pragma unroll
    for (int m = 0; m < 4; ++m)
        #pragma unroll
        for (int n = 0; n < 4; ++n) acc[m][n] = (f32x4){0.f, 0.f, 0.f, 0.f};

    int cur = 0;
    for (int step = 0; step < 32; ++step) {
        // stage next step's B into the other buffer (issued early, drained at
        // this step's barrier -> latency hidden under ds_read+MFMA)
        if (step + 1 < 32) {
            const int ncct = (step + 1) >> 3, nks = (step + 1) & 7;
            const int cg = code0 + ncct * 256;
            #pragma unroll
            for (int i = 0; i < 2; ++i) {
                const int code = cg + wave * 32 + i * 16 + (lane >> 2);
                async16((const char*)cbb_sw + (size_t)code * 512 + nks * 64
                            + (lane & 3) * 16,
                        Bs[cur ^ 1] + wave * 2048 + i * 1024);
            }
        }
        const int ks = step & 7;

        short8 af[4], bf[4];
        #pragma unroll
        for (int m = 0; m < 4; ++m) {
            const int row = wr * 64 + m * 16 + fr;
            const int s   = ((ks << 2) | kg) ^ fr;     // row&15 == fr
            af[m] = *reinterpret_cast<const short8*>(&As[row * 512 + (s << 4)]);
        }
        #pragma unroll
        for (int n = 0; n < 4; ++n) {
            const int c = wc * 64 + n * 16 + fr;
            const int s = (kg + (c >> 1)) & 3;
            bf[n] = *reinterpret_cast<const short8*>(&Bs[cur][c * 64 + (s << 4)]);
        }
        #pragma unroll
        for (int m = 0; m < 4; ++m)
            #pragma unroll
            for (int n = 0; n < 4; ++n)
                acc[m][n] = __builtin_amdgcn_mfma_f32_16x16x32_bf16(af[m], bf[n], acc[m][n], 0, 0, 0);

        __syncthreads();   // staged B (next) drained; all reads of Bs[cur] done
        cur ^= 1;

        if (ks == 7) {     // ---- per-cct epilogue (registers + private LDS)
            const int cct = step >> 3;
            float c2v[4];
            #pragma unroll
            for (int n = 0; n < 4; ++n)
                c2v[n] = c2[code0 + cct * 256 + wc * 64 + n * 16 + fr];
            #pragma unroll
            for (int m = 0; m < 4; ++m) {
                #pragma unroll
                for (int r = 0; r < 4; ++r) {
                    if (COLLECT) {
                        const int lrow = wr * 64 + m * 16 + kg * 4 + r;
                        const float thr = thr_s[lrow];
                        #pragma unroll
                        for (int n = 0; n < 4; ++n) {
                            const float v = acc[m][n][r] + c2v[n];
                            if (v <= thr) {
                                const int code = code0 + cct * 256 + wc * 64 + n * 16 + fr;
                                const int pos = atomicAdd(&qn_s, 1);
                                if (pos < BUFCAP)
                                    qbuf[pos] = ((unsigned)(rowbase + lrow) << 12) | (unsigned)code;
                            }
                        }
                    } else {
                        float v = acc[m][0][r] + c2v[0];
                        #pragma unroll
                        for (int n = 1; n < 4; ++n) v = fminf(v, acc[m][n][r] + c2v[n]);
                        runv[m][r] = fminf(runv[m][r], v);
                    }
                }
            }
            #pragma unroll
            for (int m = 0; m < 4; ++m)
                #pragma unroll
                for (int n = 0; n < 4; ++n) acc[m][n] = (f32x4){0.f, 0.f, 0.f, 0.f};
        }
    }

    if (COLLECT) {
        __syncthreads();
        if (t == 0) {
            int n = qn_s;
            if (n > BUFCAP) { atomicOr(overflow, 1u); n = BUFCAP; }
            qbase_s = (int)atomicAdd(qcnt, (unsigned)n);
            qn_s = n;
        }
        __syncthreads();
        const unsigned base = (unsigned)qbase_s;
        for (int i = t; i < qn_s; i += 512) {
            const unsigned p = base + (unsigned)i;
            if (p < QCAP) queue[p] = qbuf[i];
        }
    } else {
        // deferred MIN reduce: 16 fr-lanes (same kg) share a row
        #pragma unroll
        for (int m = 0; m < 4; ++m)
            #pragma unroll
            for (int r = 0; r < 4; ++r) {
                float v = runv[m][r];
                #pragma unroll
                for (int off = 1; off < 16; off <<= 1)
                    v = fminf(v, __shfl_xor(v, off, 64));
                if (fr == 0)
                    atomicMin(&rowmin_s[wr * 64 + m * 16 + kg * 4 + r], fmap(v));
            }
        __syncthreads();
        if (t < 128) atomicMin(&rowmin[rowbase + t], rowmin_s[t]);
    }
}

// ---------------------------------------------------------------------------
// queue rerank (+ overflow full-scan tail): one WAVE per queue entry.
// Exact fp32 score, atomicMin on (fmap(score)<<32)|code  -> lowest-index ties.
// ---------------------------------------------------------------------------
__global__ __launch_bounds__(256)
void qrerank_kernel(const float* __restrict__ x, const float* __restrict__ cb,
                    const float* __restrict__ c2,
                    const unsigned int* __restrict__ qcnt,
                    const unsigned int* __restrict__ overflow,
                    const unsigned int* __restrict__ queue,
                    unsigned long long* __restrict__ keys) {
    const int wave = threadIdx.x >> 6, lane = threadIdx.x & 63;
    const unsigned raw = *qcnt;
    const unsigned total = raw > QCAP ? QCAP : raw;
    const unsigned stride = gridDim.x * 4;
    for (unsigned e = blockIdx.x * 4 + wave; e < total; e += stride) {
        const unsigned ent = queue[e];
        const int row = (int)(ent >> 12);
        const int code = (int)(ent & 0xFFFu);
        const float4 xv = reinterpret_cast<const float4*>(x)[(size_t)row * 64 + lane];
        const float4 cv = reinterpret_cast<const float4*>(cb)[(size_t)code * 64 + lane];
        float d = fmaf(xv.x, cv.x, fmaf(xv.y, cv.y, fmaf(xv.z, cv.z, xv.w * cv.w)));
        #pragma unroll
        for (int off = 1; off < 64; off <<= 1) d += __shfl_xor(d, off, 64);
        const float s = fmaf(-2.0f, d, c2[code]);
        if (lane == 0)
            atomicMin(&keys[row],
                      ((unsigned long long)fmap(s) << 32) | (unsigned)code);
    }
    if (raw > QCAP || *overflow) {       // ~never: exact fallback
        for (int row = blockIdx.x * 4 + wave; row < VQ_N; row += gridDim.x * 4) {
            const float4 xv = reinterpret_cast<const float4*>(x)[(size_t)row * 64 + lane];
            float bv = 3.4e38f; int bk = 0;
            for (int k = 0; k < VQ_K; ++k) {
                const float4 cv = reinterpret_cast<const float4*>(cb)[(size_t)k * 64 + lane];
                float d = fmaf(xv.x, cv.x, fmaf(xv.y, cv.y, fmaf(xv.z, cv.z, xv.w * cv.w)));
                #pragma unroll
                for (int off = 1; off < 64; off <<= 1) d += __shfl_xor(d, off, 64);
                const float s = fmaf(-2.0f, d, c2[k]);
                if (s < bv) { bv = s; bk = k; }
            }
            if (lane == 0)
                atomicMin(&keys[row],
                          ((unsigned long long)fmap(bv) << 32) | (unsigned)bk);
        }
    }
}

// ---------------------------------------------------------------------------
// finalize: keys -> ind, gather, commitment-loss partials; LAST block scales
// and writes the loss (device-scope atomics + threadfence last-block pattern).
// ---------------------------------------------------------------------------
__global__ __launch_bounds__(256)
void finalize_kernel(const float* __restrict__ x, const float* __restrict__ cb,
                     const unsigned long long* __restrict__ keys,
                     float* __restrict__ out, float* __restrict__ ind_out,
                     float* __restrict__ loss_accum, unsigned int* __restrict__ done,
                     float* __restrict__ loss_out) {
    const int wave = threadIdx.x >> 6, lane = threadIdx.x & 63;
    const int row = blockIdx.x * 4 + wave;
    const int code = (int)(keys[row] & 0xFFFFFFFFull);
    const float4 qv = reinterpret_cast<const float4*>(cb)[(size_t)code * 64 + lane];
    const float4 xv = reinterpret_cast<const float4*>(x)[(size_t)row * 64 + lane];
    reinterpret_cast<float4*>(out)[(size_t)row * 64 + lane] = qv;
    if (lane == 0) ind_out[row] = (float)code;
    const float dx = qv.x - xv.x, dy = qv.y - xv.y, dz = qv.z - xv.z, dw = qv.w - xv.w;
    float s = dx * dx + dy * dy + dz * dz + dw * dw;
    #pragma unroll
    for (int off = 1; off < 64; off <<= 1) s += __shfl_xor(s, off, 64);
    __shared__ float ls[4];
    if (lane == 0) ls[wave] = s;
    __syncthreads();
    if (threadIdx.x == 0) {
        atomicAdd(loss_accum, ls[0] + ls[1] + ls[2] + ls[3]);
        __threadfence();
        const unsigned old = atomicAdd(done, 1u);
        if (old == gridDim.x - 1) {
            const float v = atomicAdd(loss_accum, 0.0f);   // coherent read
            *loss_out = v * (1.0f / ((float)VQ_N * (float)VQ_D));
        }
    }
}

// ---------------------------------------------------------------------------
// d_out: [out N*D | ind N | loss 1]. Dead-until-finalize regions host xb_sw
// (d_out[0,16MB)) and the queue (d_out[16MB,24MB)).
// ws: c2 16K | rowmin 128K | keys 256K | ctrl 64B | cbb_sw 2MB.
// 5 dispatches total, no memsets.
// ---------------------------------------------------------------------------
extern "C" void kernel_launch(void* const* d_in, const int* in_sizes, int n_in,
                              void* d_out, int out_size, void* d_ws, size_t ws_size,
                              hipStream_t stream) {
    const float* x  = (const float*)d_in[0];
    const float* cb = (const float*)d_in[1];
    float* out      = (float*)d_out;
    float* ind_out  = out + (size_t)VQ_N * VQ_D;
    float* loss_out = ind_out + VQ_N;

    char* w = (char*)d_ws;
    float*              c2     = (float*)w;                         // 16 KB
    unsigned int*       rowmin = (unsigned int*)(w + 16384);        // 128 KB
    unsigned long long* keys   = (unsigned long long*)(w + 147456); // 256 KB
    unsigned int*       ctrl   = (unsigned int*)(w + 409600);       // 64 B
    unsigned int*       qcnt       = ctrl + 0;
    unsigned int*       overflow   = ctrl + 1;
    float*              loss_accum = (float*)(ctrl + 2);
    unsigned int*       done       = ctrl + 3;
    short8*             cbb_sw = (short8*)(w + 409664);             // 2 MB

    short8*       xb_sw = (short8*)d_out;                           // 16 MB
    unsigned int* queue = (unsigned int*)((char*)d_out + (16u << 20)); // 8 MB

    prep_all_kernel<<<2433, 256, 0, stream>>>(x, cb, xb_sw, cbb_sw, c2,
                                              rowmin, keys, ctrl);

    dim3 gs(VQ_N / 128, 4);   // 256 row-blocks x 4 code-splits
    sweep_kernel<false><<<gs, 512, 0, stream>>>(xb_sw, cbb_sw, c2, rowmin,
                                                qcnt, overflow, queue);
    sweep_kernel<true ><<<gs, 512, 0, stream>>>(xb_sw, cbb_sw, c2, rowmin,
                                                qcnt, overflow, queue);

    qrerank_kernel<<<1024, 256, 0, stream>>>(x, cb, c2, qcnt, overflow, queue, keys);

    finalize_kernel<<<VQ_N / 4, 256, 0, stream>>>(x, cb, keys, out, ind_out,
                                                  loss_accum, done, loss_out);
}

// Round 7
// 361.981 us; speedup vs baseline: 1.7276x; 1.7276x over previous
//
#include <hip/hip_runtime.h>
#include <hip/hip_bf16.h>

// N=32768 queries, D=256 dims, K=4096 codes (fp32 in/out).
#define VQ_N 32768
#define VQ_D 256
#define VQ_K 4096
#define BAND 16.0f                 // >= 2 * worst-case bf16 score error (~3.7)
#define QCAP (2u * 1024u * 1024u)  // global queue capacity (u32 entries)
#define BUFCAP 2048                // per-block LDS queue buffer

typedef __attribute__((ext_vector_type(8))) short short8;  // 8 bf16 (4 VGPRs)
typedef __attribute__((ext_vector_type(4))) float f32x4;   // MFMA C/D frag

// monotone float<->uint map (total order incl. negatives)
__device__ __forceinline__ unsigned fmap(float f) {
    unsigned b = __float_as_uint(f);
    return (b & 0x80000000u) ? ~b : (b | 0x80000000u);
}
__device__ __forceinline__ float fmapinv(unsigned u) {
    unsigned b = (u & 0x80000000u) ? (u & 0x7FFFFFFFu) : ~u;
    return __uint_as_float(b);
}

// async global->LDS: global src is PER-LANE, LDS dest is wave-uniform base,
// HW writes base + lane*16.
__device__ __forceinline__ void async16(const void* g, void* l) {
    __builtin_amdgcn_global_load_lds(
        (const __attribute__((address_space(1))) unsigned int*)g,
        (__attribute__((address_space(3))) unsigned int*)l, 16, 0, 0);
}

__device__ __forceinline__ short8 pack8(float4 a, float4 b) {
    union { __hip_bfloat16 h[8]; short8 s8; } u;
    u.h[0] = __float2bfloat16(a.x); u.h[1] = __float2bfloat16(a.y);
    u.h[2] = __float2bfloat16(a.z); u.h[3] = __float2bfloat16(a.w);
    u.h[4] = __float2bfloat16(b.x); u.h[5] = __float2bfloat16(b.y);
    u.h[6] = __float2bfloat16(b.z); u.h[7] = __float2bfloat16(b.w);
    return u.s8;
}

// ---------------------------------------------------------------------------
// prep_all: one fused kernel (2 preps + c2 + all control/buffer inits).
//  blocks [0,2048):    xb_sw  — bf16 x in A-swizzled slot order
//                      slot s of row holds k-quad q = s ^ (row&15)  (8 bf16)
//  blocks [2048,2304): cbb_sw — bf16 -2*cb in B-swizzled order + c2 (fp32)
//                      slot j=ks*4+sl of code holds kq = (sl - (code>>1))&3
//  blocks [2304,2432): rowmin/keys init
//  block  2432:        qcnt/overflow init
// ---------------------------------------------------------------------------
__global__ __launch_bounds__(256)
void prep_all_kernel(const float* __restrict__ x, const float* __restrict__ cb,
                     short8* __restrict__ xb_sw, short8* __restrict__ cbb_sw,
                     float* __restrict__ c2, unsigned int* __restrict__ rowmin,
                     unsigned long long* __restrict__ keys,
                     unsigned int* __restrict__ ctrl /*qcnt,ovf*/) {
    const int b = blockIdx.x, t = threadIdx.x;
    if (b < 2048) {                       // ---- xb_sw: 16 rows per block
        #pragma unroll
        for (int h = 0; h < 2; ++h) {
            const int u   = t + h * 256;            // 0..511 slot-units
            const int row = b * 16 + (u >> 5);
            const int s   = u & 31;
            const int q   = s ^ (row & 15);
            const float4 a = reinterpret_cast<const float4*>(x)[(size_t)row * 64 + q * 2];
            const float4 c = reinterpret_cast<const float4*>(x)[(size_t)row * 64 + q * 2 + 1];
            xb_sw[(size_t)row * 32 + s] = pack8(a, c);
        }
    } else if (b < 2304) {                // ---- cbb_sw + c2: 16 codes per block
        const int code = (b - 2048) * 16 + (t >> 4);
        float ss = 0.0f;
        #pragma unroll
        for (int h = 0; h < 2; ++h) {
            const int j  = (t & 15) * 2 + h;        // 0..31
            const int ks = j >> 2, sl = j & 3;
            const int kq = (sl - (code >> 1)) & 3;
            const int k  = ks * 32 + kq * 8;
            const float4 a = reinterpret_cast<const float4*>(cb)[(size_t)code * 64 + k / 4];
            const float4 c = reinterpret_cast<const float4*>(cb)[(size_t)code * 64 + k / 4 + 1];
            ss += a.x*a.x + a.y*a.y + a.z*a.z + a.w*a.w
                + c.x*c.x + c.y*c.y + c.z*c.z + c.w*c.w;
            const float4 na = make_float4(-2.f*a.x, -2.f*a.y, -2.f*a.z, -2.f*a.w);
            const float4 nc = make_float4(-2.f*c.x, -2.f*c.y, -2.f*c.z, -2.f*c.w);
            cbb_sw[(size_t)code * 32 + j] = pack8(na, nc);
        }
        #pragma unroll
        for (int off = 1; off < 16; off <<= 1) ss += __shfl_xor(ss, off, 64);
        if ((t & 15) == 0) c2[code] = ss;
    } else if (b < 2432) {                // ---- rowmin + keys init
        const int i = (b - 2304) * 256 + t;
        rowmin[i] = 0xFFFFFFFFu;
        keys[i]   = ~0ull;
    } else {                              // ---- control words
        if (t < 8) ctrl[t] = 0u;
    }
}

// ---------------------------------------------------------------------------
// A-resident MFMA sweep (unchanged from round 6 — known-passing).
// Block = 128 rows x 1024 codes (gridDim.y=4 splits). A-tile (64KB, swizzled)
// staged ONCE; B double-buffered (16KB/step). 8 waves (2x4), 64x64 per wave,
// 16 MFMA + 8 ds_read_b128 per step, ONE barrier per step.
// ---------------------------------------------------------------------------
template<bool COLLECT>
__global__ __launch_bounds__(512, 2)
void sweep_kernel(const short8* __restrict__ xb_sw,
                  const short8* __restrict__ cbb_sw,
                  const float* __restrict__ c2,
                  unsigned int* __restrict__ rowmin,
                  unsigned int* __restrict__ qcnt,
                  unsigned int* __restrict__ overflow,
                  unsigned int* __restrict__ queue) {
    __shared__ __attribute__((aligned(16))) char As[128 * 512];      // 64 KB
    __shared__ __attribute__((aligned(16))) char Bs[2][256 * 64];    // 2x16 KB
    __shared__ unsigned int rowmin_s[128];
    __shared__ float        thr_s[128];
    __shared__ unsigned int qbuf[BUFCAP];
    __shared__ int qn_s, qbase_s;

    const int t = threadIdx.x;
    const int lane = t & 63, wave = t >> 6;        // 8 waves
    const int wr = wave >> 2, wc = wave & 3;       // 2x4: 64-row x 64-code tile
    const int fr = lane & 15, kg = lane >> 4;
    const int rowbase = blockIdx.x * 128;
    const int code0   = blockIdx.y * 1024;

    if (COLLECT) {
        if (t < 128) thr_s[t] = fmapinv(rowmin[rowbase + t]) + BAND;
        if (t == 0) qn_s = 0;
    } else {
        if (t < 128) rowmin_s[t] = 0xFFFFFFFFu;
    }

    // ---- stage A once: wave w covers rows [w*16, w*16+16), linear 16B slots
    {
        const char* asrc = (const char*)xb_sw + (size_t)rowbase * 512 + wave * 8192
                           + lane * 16;
        char* adst = As + wave * 8192;
        #pragma unroll
        for (int i = 0; i < 8; ++i)
            async16(asrc + i * 1024, adst + i * 1024);
    }
    // ---- stage B step 0 (cct=0, ks=0) into buf 0
    {
        const int cg0 = code0;
        #pragma unroll
        for (int i = 0; i < 2; ++i) {
            const int code = cg0 + wave * 32 + i * 16 + (lane >> 2);
            async16((const char*)cbb_sw + (size_t)code * 512 + (lane & 3) * 16,
                    Bs[0] + wave * 2048 + i * 1024);
        }
    }
    __syncthreads();                               // drains A + B0

    float runv[4][4];
    #pragma unroll
    for (int m = 0; m < 4; ++m)
        #pragma unroll
        for (int r = 0; r < 4; ++r) runv[m][r] = 3.4e38f;

    f32x4 acc[4][4];
    #pragma unroll
    for (int m = 0; m < 4; ++m)
        #pragma unroll
        for (int n = 0; n < 4; ++n) acc[m][n] = (f32x4){0.f, 0.f, 0.f, 0.f};

    int cur = 0;
    for (int step = 0; step < 32; ++step) {
        if (step + 1 < 32) {
            const int ncct = (step + 1) >> 3, nks = (step + 1) & 7;
            const int cg = code0 + ncct * 256;
            #pragma unroll
            for (int i = 0; i < 2; ++i) {
                const int code = cg + wave * 32 + i * 16 + (lane >> 2);
                async16((const char*)cbb_sw + (size_t)code * 512 + nks * 64
                            + (lane & 3) * 16,
                        Bs[cur ^ 1] + wave * 2048 + i * 1024);
            }
        }
        const int ks = step & 7;

        short8 af[4], bf[4];
        #pragma unroll
        for (int m = 0; m < 4; ++m) {
            const int row = wr * 64 + m * 16 + fr;
            const int s   = ((ks << 2) | kg) ^ fr;     // row&15 == fr
            af[m] = *reinterpret_cast<const short8*>(&As[row * 512 + (s << 4)]);
        }
        #pragma unroll
        for (int n = 0; n < 4; ++n) {
            const int c = wc * 64 + n * 16 + fr;
            const int s = (kg + (c >> 1)) & 3;
            bf[n] = *reinterpret_cast<const short8*>(&Bs[cur][c * 64 + (s << 4)]);
        }
        #pragma unroll
        for (int m = 0; m < 4; ++m)
            #pragma unroll
            for (int n = 0; n < 4; ++n)
                acc[m][n] = __builtin_amdgcn_mfma_f32_16x16x32_bf16(af[m], bf[n], acc[m][n], 0, 0, 0);

        __syncthreads();   // staged B (next) drained; all reads of Bs[cur] done
        cur ^= 1;

        if (ks == 7) {     // ---- per-cct epilogue
            const int cct = step >> 3;
            float c2v[4];
            #pragma unroll
            for (int n = 0; n < 4; ++n)
                c2v[n] = c2[code0 + cct * 256 + wc * 64 + n * 16 + fr];
            #pragma unroll
            for (int m = 0; m < 4; ++m) {
                #pragma unroll
                for (int r = 0; r < 4; ++r) {
                    if (COLLECT) {
                        const int lrow = wr * 64 + m * 16 + kg * 4 + r;
                        const float thr = thr_s[lrow];
                        #pragma unroll
                        for (int n = 0; n < 4; ++n) {
                            const float v = acc[m][n][r] + c2v[n];
                            if (v <= thr) {
                                const int code = code0 + cct * 256 + wc * 64 + n * 16 + fr;
                                const int pos = atomicAdd(&qn_s, 1);
                                if (pos < BUFCAP)
                                    qbuf[pos] = ((unsigned)(rowbase + lrow) << 12) | (unsigned)code;
                            }
                        }
                    } else {
                        float v = acc[m][0][r] + c2v[0];
                        #pragma unroll
                        for (int n = 1; n < 4; ++n) v = fminf(v, acc[m][n][r] + c2v[n]);
                        runv[m][r] = fminf(runv[m][r], v);
                    }
                }
            }
            #pragma unroll
            for (int m = 0; m < 4; ++m)
                #pragma unroll
                for (int n = 0; n < 4; ++n) acc[m][n] = (f32x4){0.f, 0.f, 0.f, 0.f};
        }
    }

    if (COLLECT) {
        __syncthreads();
        if (t == 0) {
            int n = qn_s;
            if (n > BUFCAP) { atomicOr(overflow, 1u); n = BUFCAP; }
            qbase_s = (int)atomicAdd(qcnt, (unsigned)n);
            qn_s = n;
        }
        __syncthreads();
        const unsigned base = (unsigned)qbase_s;
        for (int i = t; i < qn_s; i += 512) {
            const unsigned p = base + (unsigned)i;
            if (p < QCAP) queue[p] = qbuf[i];
        }
    } else {
        #pragma unroll
        for (int m = 0; m < 4; ++m)
            #pragma unroll
            for (int r = 0; r < 4; ++r) {
                float v = runv[m][r];
                #pragma unroll
                for (int off = 1; off < 16; off <<= 1)
                    v = fminf(v, __shfl_xor(v, off, 64));
                if (fr == 0)
                    atomicMin(&rowmin_s[wr * 64 + m * 16 + kg * 4 + r], fmap(v));
            }
        __syncthreads();
        if (t < 128) atomicMin(&rowmin[rowbase + t], rowmin_s[t]);
    }
}

// ---------------------------------------------------------------------------
// queue rerank: one entry per 16-lane QUARTER-wave (4x parallelism of wave-
// per-entry, 4-level reduce). Exact fp32 score, atomicMin on
// (fmap(score)<<32)|code -> lowest-index tie-break. Overflow tail: full scan.
// ---------------------------------------------------------------------------
__global__ __launch_bounds__(256)
void qrerank_kernel(const float* __restrict__ x, const float* __restrict__ cb,
                    const float* __restrict__ c2,
                    const unsigned int* __restrict__ qcnt,
                    const unsigned int* __restrict__ overflow,
                    const unsigned int* __restrict__ queue,
                    unsigned long long* __restrict__ keys) {
    const int t = threadIdx.x;
    const int g  = t >> 4;               // 16 quarter-wave groups per block
    const int sl = t & 15;
    const unsigned raw = *qcnt;
    const unsigned total = raw > QCAP ? QCAP : raw;
    const unsigned stride = gridDim.x * 16;
    for (unsigned e = blockIdx.x * 16 + g; e < total; e += stride) {
        const unsigned ent = queue[e];
        const int row = (int)(ent >> 12);
        const int code = (int)(ent & 0xFFFu);
        float d = 0.0f;
        #pragma unroll
        for (int i = 0; i < 4; ++i) {
            const float4 xv = reinterpret_cast<const float4*>(x)[(size_t)row * 64 + i * 16 + sl];
            const float4 cv = reinterpret_cast<const float4*>(cb)[(size_t)code * 64 + i * 16 + sl];
            d += xv.x * cv.x + xv.y * cv.y + xv.z * cv.z + xv.w * cv.w;
        }
        #pragma unroll
        for (int off = 1; off < 16; off <<= 1) d += __shfl_xor(d, off, 64);
        const float s = fmaf(-2.0f, d, c2[code]);
        if (sl == 0)
            atomicMin(&keys[row],
                      ((unsigned long long)fmap(s) << 32) | (unsigned)code);
    }
    if (raw > QCAP || *overflow) {       // ~never: exact fallback, wave/row
        const int wave = t >> 6, lane = t & 63;
        for (int row = blockIdx.x * 4 + wave; row < VQ_N; row += gridDim.x * 4) {
            const float4 xv = reinterpret_cast<const float4*>(x)[(size_t)row * 64 + lane];
            float bv = 3.4e38f; int bk = 0;
            for (int k = 0; k < VQ_K; ++k) {
                const float4 cv = reinterpret_cast<const float4*>(cb)[(size_t)k * 64 + lane];
                float d = fmaf(xv.x, cv.x, fmaf(xv.y, cv.y, fmaf(xv.z, cv.z, xv.w * cv.w)));
                #pragma unroll
                for (int off = 1; off < 64; off <<= 1) d += __shfl_xor(d, off, 64);
                const float s = fmaf(-2.0f, d, c2[k]);
                if (s < bv) { bv = s; bk = k; }
            }
            if (lane == 0)
                atomicMin(&keys[row],
                          ((unsigned long long)fmap(bv) << 32) | (unsigned)bk);
        }
    }
}

// ---------------------------------------------------------------------------
// finalize: keys -> ind, gather, per-block loss partial via PLAIN STORE
// (no global atomics, no fence — round-6's single-address atomic chain was
// 250 us of serialization). partials[] reuses the dead rowmin buffer.
// ---------------------------------------------------------------------------
__global__ __launch_bounds__(256)
void finalize_kernel(const float* __restrict__ x, const float* __restrict__ cb,
                     const unsigned long long* __restrict__ keys,
                     float* __restrict__ out, float* __restrict__ ind_out,
                     float* __restrict__ partials) {
    const int wave = threadIdx.x >> 6, lane = threadIdx.x & 63;
    const int row = blockIdx.x * 4 + wave;
    const int code = (int)(keys[row] & 0xFFFFFFFFull);
    const float4 qv = reinterpret_cast<const float4*>(cb)[(size_t)code * 64 + lane];
    const float4 xv = reinterpret_cast<const float4*>(x)[(size_t)row * 64 + lane];
    reinterpret_cast<float4*>(out)[(size_t)row * 64 + lane] = qv;
    if (lane == 0) ind_out[row] = (float)code;
    const float dx = qv.x - xv.x, dy = qv.y - xv.y, dz = qv.z - xv.z, dw = qv.w - xv.w;
    float s = dx * dx + dy * dy + dz * dz + dw * dw;
    #pragma unroll
    for (int off = 1; off < 64; off <<= 1) s += __shfl_xor(s, off, 64);
    __shared__ float ls[4];
    if (lane == 0) ls[wave] = s;
    __syncthreads();
    if (threadIdx.x == 0) partials[blockIdx.x] = ls[0] + ls[1] + ls[2] + ls[3];
}

// single small block: reduce 8192 partials, scale, write loss
__global__ __launch_bounds__(256)
void loss_reduce_kernel(const float* __restrict__ partials,
                        float* __restrict__ loss_out) {
    const int wave = threadIdx.x >> 6, lane = threadIdx.x & 63;
    float s = 0.0f;
    for (int i = threadIdx.x; i < VQ_N / 4; i += 256) s += partials[i];
    #pragma unroll
    for (int off = 1; off < 64; off <<= 1) s += __shfl_xor(s, off, 64);
    __shared__ float ls[4];
    if (lane == 0) ls[wave] = s;
    __syncthreads();
    if (threadIdx.x == 0)
        *loss_out = (ls[0] + ls[1] + ls[2] + ls[3])
                    * (1.0f / ((float)VQ_N * (float)VQ_D));
}

// ---------------------------------------------------------------------------
// d_out: [out N*D | ind N | loss 1]. Dead-until-finalize regions host xb_sw
// (d_out[0,16MB)) and the queue (d_out[16MB,24MB)).
// ws: c2 16K | rowmin 128K (reused as loss partials by finalize) | keys 256K
//     | ctrl 64B | cbb_sw 2MB.   6 dispatches, no memsets, no device atomics
//     on shared addresses outside the sweeps' distributed ones.
// ---------------------------------------------------------------------------
extern "C" void kernel_launch(void* const* d_in, const int* in_sizes, int n_in,
                              void* d_out, int out_size, void* d_ws, size_t ws_size,
                              hipStream_t stream) {
    const float* x  = (const float*)d_in[0];
    const float* cb = (const float*)d_in[1];
    float* out      = (float*)d_out;
    float* ind_out  = out + (size_t)VQ_N * VQ_D;
    float* loss_out = ind_out + VQ_N;

    char* w = (char*)d_ws;
    float*              c2     = (float*)w;                         // 16 KB
    unsigned int*       rowmin = (unsigned int*)(w + 16384);        // 128 KB
    unsigned long long* keys   = (unsigned long long*)(w + 147456); // 256 KB
    unsigned int*       ctrl   = (unsigned int*)(w + 409600);       // 64 B
    unsigned int*       qcnt     = ctrl + 0;
    unsigned int*       overflow = ctrl + 1;
    short8*             cbb_sw = (short8*)(w + 409664);             // 2 MB
    float*              partials = (float*)rowmin;   // rowmin dead by finalize

    short8*       xb_sw = (short8*)d_out;                           // 16 MB
    unsigned int* queue = (unsigned int*)((char*)d_out + (16u << 20)); // 8 MB

    prep_all_kernel<<<2433, 256, 0, stream>>>(x, cb, xb_sw, cbb_sw, c2,
                                              rowmin, keys, ctrl);

    dim3 gs(VQ_N / 128, 4);   // 256 row-blocks x 4 code-splits
    sweep_kernel<false><<<gs, 512, 0, stream>>>(xb_sw, cbb_sw, c2, rowmin,
                                                qcnt, overflow, queue);
    sweep_kernel<true ><<<gs, 512, 0, stream>>>(xb_sw, cbb_sw, c2, rowmin,
                                                qcnt, overflow, queue);

    qrerank_kernel<<<1024, 256, 0, stream>>>(x, cb, c2, qcnt, overflow, queue, keys);

    finalize_kernel<<<VQ_N / 4, 256, 0, stream>>>(x, cb, keys, out, ind_out,
                                                  partials);
    loss_reduce_kernel<<<1, 256, 0, stream>>>(partials, loss_out);
}

// Round 8
// 345.172 us; speedup vs baseline: 1.8117x; 1.0487x over previous
//
#include <hip/hip_runtime.h>
#include <hip/hip_bf16.h>

// N=32768 queries, D=256 dims, K=4096 codes (fp32 in/out).
#define VQ_N 32768
#define VQ_D 256
#define VQ_K 4096
#define BAND 16.0f                 // >= 2 * worst-case bf16 score error (~6)
#define QCAP (2u * 1024u * 1024u)  // global queue capacity (u32 entries)
#define BUFCAP 4096                // per-block LDS queue buffer

typedef __attribute__((ext_vector_type(8))) short short8;  // 8 bf16 (4 VGPRs)
typedef __attribute__((ext_vector_type(4))) float f32x4;   // MFMA C/D frag

// monotone float<->uint map (total order incl. negatives)
__device__ __forceinline__ unsigned fmap(float f) {
    unsigned b = __float_as_uint(f);
    return (b & 0x80000000u) ? ~b : (b | 0x80000000u);
}
__device__ __forceinline__ float fmapinv(unsigned u) {
    unsigned b = (u & 0x80000000u) ? (u & 0x7FFFFFFFu) : ~u;
    return __uint_as_float(b);
}

// async global->LDS: global src is PER-LANE, LDS dest is wave-uniform base,
// HW writes base + lane*16.
__device__ __forceinline__ void async16(const void* g, void* l) {
    __builtin_amdgcn_global_load_lds(
        (const __attribute__((address_space(1))) unsigned int*)g,
        (__attribute__((address_space(3))) unsigned int*)l, 16, 0, 0);
}

__device__ __forceinline__ short8 pack8(float4 a, float4 b) {
    union { __hip_bfloat16 h[8]; short8 s8; } u;
    u.h[0] = __float2bfloat16(a.x); u.h[1] = __float2bfloat16(a.y);
    u.h[2] = __float2bfloat16(a.z); u.h[3] = __float2bfloat16(a.w);
    u.h[4] = __float2bfloat16(b.x); u.h[5] = __float2bfloat16(b.y);
    u.h[6] = __float2bfloat16(b.z); u.h[7] = __float2bfloat16(b.w);
    return u.s8;
}

// ---------------------------------------------------------------------------
// prep_all: fused fp32->bf16 swizzled layouts + c2 + inits.
//  blocks [0,2048):    xb_sw  — bf16 x, slot s of row holds k-quad q=s^(row&15)
//  blocks [2048,2304): cbb_sw — bf16 -2*cb, slot j=ks*4+sl holds
//                      kq=(sl-(code>>1))&3; plus c2 (fp32 norms)
//  blocks [2304,2432): keys init
//  block  2432:        qcnt/overflow init
// ---------------------------------------------------------------------------
__global__ __launch_bounds__(256)
void prep_all_kernel(const float* __restrict__ x, const float* __restrict__ cb,
                     short8* __restrict__ xb_sw, short8* __restrict__ cbb_sw,
                     float* __restrict__ c2,
                     unsigned long long* __restrict__ keys,
                     unsigned int* __restrict__ ctrl /*qcnt,ovf*/) {
    const int b = blockIdx.x, t = threadIdx.x;
    if (b < 2048) {                       // ---- xb_sw: 16 rows per block
        #pragma unroll
        for (int h = 0; h < 2; ++h) {
            const int u   = t + h * 256;            // 0..511 slot-units
            const int row = b * 16 + (u >> 5);
            const int s   = u & 31;
            const int q   = s ^ (row & 15);
            const float4 a = reinterpret_cast<const float4*>(x)[(size_t)row * 64 + q * 2];
            const float4 c = reinterpret_cast<const float4*>(x)[(size_t)row * 64 + q * 2 + 1];
            xb_sw[(size_t)row * 32 + s] = pack8(a, c);
        }
    } else if (b < 2304) {                // ---- cbb_sw + c2: 16 codes per block
        const int code = (b - 2048) * 16 + (t >> 4);
        float ss = 0.0f;
        #pragma unroll
        for (int h = 0; h < 2; ++h) {
            const int j  = (t & 15) * 2 + h;        // 0..31
            const int ks = j >> 2, sl = j & 3;
            const int kq = (sl - (code >> 1)) & 3;
            const int k  = ks * 32 + kq * 8;
            const float4 a = reinterpret_cast<const float4*>(cb)[(size_t)code * 64 + k / 4];
            const float4 c = reinterpret_cast<const float4*>(cb)[(size_t)code * 64 + k / 4 + 1];
            ss += a.x*a.x + a.y*a.y + a.z*a.z + a.w*a.w
                + c.x*c.x + c.y*c.y + c.z*c.z + c.w*c.w;
            const float4 na = make_float4(-2.f*a.x, -2.f*a.y, -2.f*a.z, -2.f*a.w);
            const float4 nc = make_float4(-2.f*c.x, -2.f*c.y, -2.f*c.z, -2.f*c.w);
            cbb_sw[(size_t)code * 32 + j] = pack8(na, nc);
        }
        #pragma unroll
        for (int off = 1; off < 16; off <<= 1) ss += __shfl_xor(ss, off, 64);
        if ((t & 15) == 0) c2[code] = ss;
    } else if (b < 2432) {                // ---- keys init
        keys[(b - 2304) * 256 + t] = ~0ull;
    } else {                              // ---- control words
        if (t < 8) ctrl[t] = 0u;
    }
}

// ---------------------------------------------------------------------------
// SINGLE-PASS A-resident MFMA sweep. Block = 128 rows x ALL 4096 codes
// (grid = 256 = 1 block/CU). A-tile (64KB, swizzled) staged ONCE; B
// double-buffered (16KB/step), 128 steps (16 ccts x 8 ks). 8 waves (2x4),
// 64x64 per wave, 16 MFMA + 8 conflict-free ds_read_b128 per step.
// Per cct: update LDS running row-min, barrier, collect codes with
// s~ <= runmin + BAND (running min >= final min -> SUPERSET of the two-pass
// candidate set -> exact rerank unchanged). Queue flushed once at block end.
// ---------------------------------------------------------------------------
__global__ __launch_bounds__(512, 2)
void sweep_kernel(const short8* __restrict__ xb_sw,
                  const short8* __restrict__ cbb_sw,
                  const float* __restrict__ c2,
                  unsigned int* __restrict__ qcnt,
                  unsigned int* __restrict__ overflow,
                  unsigned int* __restrict__ queue) {
    __shared__ __attribute__((aligned(16))) char As[128 * 512];      // 64 KB
    __shared__ __attribute__((aligned(16))) char Bs[2][256 * 64];    // 2x16 KB
    __shared__ unsigned int rowmin_s[128];   // running row-min (fmap'd)
    __shared__ unsigned int qbuf[BUFCAP];    // 16 KB
    __shared__ int qn_s, qbase_s;

    const int t = threadIdx.x;
    const int lane = t & 63, wave = t >> 6;        // 8 waves
    const int wr = wave >> 2, wc = wave & 3;       // 2x4: 64-row x 64-code tile
    const int fr = lane & 15, kg = lane >> 4;
    const int rowbase = blockIdx.x * 128;

    if (t < 128) rowmin_s[t] = 0xFFFFFFFFu;
    if (t == 0) qn_s = 0;

    // ---- stage A once: wave w covers rows [w*16, w*16+16), linear 16B slots
    {
        const char* asrc = (const char*)xb_sw + (size_t)rowbase * 512 + wave * 8192
                           + lane * 16;
        char* adst = As + wave * 8192;
        #pragma unroll
        for (int i = 0; i < 8; ++i)
            async16(asrc + i * 1024, adst + i * 1024);
    }
    // ---- stage B step 0 (cct=0, ks=0) into buf 0
    #pragma unroll
    for (int i = 0; i < 2; ++i) {
        const int code = wave * 32 + i * 16 + (lane >> 2);
        async16((const char*)cbb_sw + (size_t)code * 512 + (lane & 3) * 16,
                Bs[0] + wave * 2048 + i * 1024);
    }
    __syncthreads();                               // drains A + B0

    f32x4 acc[4][4];
    #pragma unroll
    for (int m = 0; m < 4; ++m)
        #pragma unroll
        for (int n = 0; n < 4; ++n) acc[m][n] = (f32x4){0.f, 0.f, 0.f, 0.f};

    int cur = 0;
    for (int step = 0; step < 128; ++step) {       // 16 ccts x 8 ks
        if (step + 1 < 128) {
            const int ncct = (step + 1) >> 3, nks = (step + 1) & 7;
            #pragma unroll
            for (int i = 0; i < 2; ++i) {
                const int code = ncct * 256 + wave * 32 + i * 16 + (lane >> 2);
                async16((const char*)cbb_sw + (size_t)code * 512 + nks * 64
                            + (lane & 3) * 16,
                        Bs[cur ^ 1] + wave * 2048 + i * 1024);
            }
        }
        const int ks = step & 7;

        short8 af[4], bf[4];
        #pragma unroll
        for (int m = 0; m < 4; ++m) {
            const int row = wr * 64 + m * 16 + fr;
            const int s   = ((ks << 2) | kg) ^ fr;     // row&15 == fr
            af[m] = *reinterpret_cast<const short8*>(&As[row * 512 + (s << 4)]);
        }
        #pragma unroll
        for (int n = 0; n < 4; ++n) {
            const int c = wc * 64 + n * 16 + fr;
            const int s = (kg + (c >> 1)) & 3;
            bf[n] = *reinterpret_cast<const short8*>(&Bs[cur][c * 64 + (s << 4)]);
        }
        #pragma unroll
        for (int m = 0; m < 4; ++m)
            #pragma unroll
            for (int n = 0; n < 4; ++n)
                acc[m][n] = __builtin_amdgcn_mfma_f32_16x16x32_bf16(af[m], bf[n], acc[m][n], 0, 0, 0);

        __syncthreads();   // staged next-B drained; all reads of Bs[cur] done
        cur ^= 1;

        if (ks == 7) {     // ---- per-cct epilogue: min-update, then collect
            const int cct = step >> 3;
            float c2v[4];
            #pragma unroll
            for (int n = 0; n < 4; ++n)
                c2v[n] = c2[cct * 256 + wc * 64 + n * 16 + fr];

            // (1) fold this cct into the running row-min
            #pragma unroll
            for (int m = 0; m < 4; ++m) {
                #pragma unroll
                for (int r = 0; r < 4; ++r) {
                    float v = acc[m][0][r] + c2v[0];
                    #pragma unroll
                    for (int n = 1; n < 4; ++n) v = fminf(v, acc[m][n][r] + c2v[n]);
                    #pragma unroll
                    for (int off = 1; off < 16; off <<= 1)
                        v = fminf(v, __shfl_xor(v, off, 64));  // 16 fr-lanes/row
                    if (fr == 0)
                        atomicMin(&rowmin_s[wr * 64 + m * 16 + kg * 4 + r], fmap(v));
                }
            }
            __syncthreads();   // running min (incl. this cct) visible

            // (2) collect codes within BAND of the running min (superset)
            #pragma unroll
            for (int m = 0; m < 4; ++m) {
                #pragma unroll
                for (int r = 0; r < 4; ++r) {
                    const int lrow = wr * 64 + m * 16 + kg * 4 + r;
                    const float thr = fmapinv(rowmin_s[lrow]) + BAND;
                    #pragma unroll
                    for (int n = 0; n < 4; ++n) {
                        const float v = acc[m][n][r] + c2v[n];
                        if (v <= thr) {
                            const int code = cct * 256 + wc * 64 + n * 16 + fr;
                            const int pos = atomicAdd(&qn_s, 1);
                            if (pos < BUFCAP)
                                qbuf[pos] = ((unsigned)(rowbase + lrow) << 12) | (unsigned)code;
                        }
                    }
                }
            }
            #pragma unroll
            for (int m = 0; m < 4; ++m)
                #pragma unroll
                for (int n = 0; n < 4; ++n) acc[m][n] = (f32x4){0.f, 0.f, 0.f, 0.f};
        }
    }

    // ---- flush queue once per block
    __syncthreads();
    if (t == 0) {
        int n = qn_s;
        if (n > BUFCAP) { atomicOr(overflow, 1u); n = BUFCAP; }
        qbase_s = (int)atomicAdd(qcnt, (unsigned)n);
        qn_s = n;
    }
    __syncthreads();
    const unsigned base = (unsigned)qbase_s;
    for (int i = t; i < qn_s; i += 512) {
        const unsigned p = base + (unsigned)i;
        if (p < QCAP) queue[p] = qbuf[i];
    }
}

// ---------------------------------------------------------------------------
// queue rerank: one entry per 16-lane quarter-wave. Exact fp32 score,
// atomicMin on (fmap(score)<<32)|code -> lowest-index tie-break.
// Overflow tail (~never): full exact scan.
// ---------------------------------------------------------------------------
__global__ __launch_bounds__(256)
void qrerank_kernel(const float* __restrict__ x, const float* __restrict__ cb,
                    const float* __restrict__ c2,
                    const unsigned int* __restrict__ qcnt,
                    const unsigned int* __restrict__ overflow,
                    const unsigned int* __restrict__ queue,
                    unsigned long long* __restrict__ keys) {
    const int t = threadIdx.x;
    const int g  = t >> 4;               // 16 quarter-wave groups per block
    const int sl = t & 15;
    const unsigned raw = *qcnt;
    const unsigned total = raw > QCAP ? QCAP : raw;
    const unsigned stride = gridDim.x * 16;
    for (unsigned e = blockIdx.x * 16 + g; e < total; e += stride) {
        const unsigned ent = queue[e];
        const int row = (int)(ent >> 12);
        const int code = (int)(ent & 0xFFFu);
        float d = 0.0f;
        #pragma unroll
        for (int i = 0; i < 4; ++i) {
            const float4 xv = reinterpret_cast<const float4*>(x)[(size_t)row * 64 + i * 16 + sl];
            const float4 cv = reinterpret_cast<const float4*>(cb)[(size_t)code * 64 + i * 16 + sl];
            d += xv.x * cv.x + xv.y * cv.y + xv.z * cv.z + xv.w * cv.w;
        }
        #pragma unroll
        for (int off = 1; off < 16; off <<= 1) d += __shfl_xor(d, off, 64);
        const float s = fmaf(-2.0f, d, c2[code]);
        if (sl == 0)
            atomicMin(&keys[row],
                      ((unsigned long long)fmap(s) << 32) | (unsigned)code);
    }
    if (raw > QCAP || *overflow) {       // ~never: exact fallback, wave/row
        const int wave = t >> 6, lane = t & 63;
        for (int row = blockIdx.x * 4 + wave; row < VQ_N; row += gridDim.x * 4) {
            const float4 xv = reinterpret_cast<const float4*>(x)[(size_t)row * 64 + lane];
            float bv = 3.4e38f; int bk = 0;
            for (int k = 0; k < VQ_K; ++k) {
                const float4 cv = reinterpret_cast<const float4*>(cb)[(size_t)k * 64 + lane];
                float d = fmaf(xv.x, cv.x, fmaf(xv.y, cv.y, fmaf(xv.z, cv.z, xv.w * cv.w)));
                #pragma unroll
                for (int off = 1; off < 64; off <<= 1) d += __shfl_xor(d, off, 64);
                const float s = fmaf(-2.0f, d, c2[k]);
                if (s < bv) { bv = s; bk = k; }
            }
            if (lane == 0)
                atomicMin(&keys[row],
                          ((unsigned long long)fmap(bv) << 32) | (unsigned)bk);
        }
    }
}

// ---------------------------------------------------------------------------
// finalize: keys -> ind, gather, per-block loss partial via plain store.
// ---------------------------------------------------------------------------
__global__ __launch_bounds__(256)
void finalize_kernel(const float* __restrict__ x, const float* __restrict__ cb,
                     const unsigned long long* __restrict__ keys,
                     float* __restrict__ out, float* __restrict__ ind_out,
                     float* __restrict__ partials) {
    const int wave = threadIdx.x >> 6, lane = threadIdx.x & 63;
    const int row = blockIdx.x * 4 + wave;
    const int code = (int)(keys[row] & 0xFFFFFFFFull);
    const float4 qv = reinterpret_cast<const float4*>(cb)[(size_t)code * 64 + lane];
    const float4 xv = reinterpret_cast<const float4*>(x)[(size_t)row * 64 + lane];
    reinterpret_cast<float4*>(out)[(size_t)row * 64 + lane] = qv;
    if (lane == 0) ind_out[row] = (float)code;
    const float dx = qv.x - xv.x, dy = qv.y - xv.y, dz = qv.z - xv.z, dw = qv.w - xv.w;
    float s = dx * dx + dy * dy + dz * dz + dw * dw;
    #pragma unroll
    for (int off = 1; off < 64; off <<= 1) s += __shfl_xor(s, off, 64);
    __shared__ float ls[4];
    if (lane == 0) ls[wave] = s;
    __syncthreads();
    if (threadIdx.x == 0) partials[blockIdx.x] = ls[0] + ls[1] + ls[2] + ls[3];
}

// single small block: reduce 8192 partials, scale, write loss
__global__ __launch_bounds__(256)
void loss_reduce_kernel(const float* __restrict__ partials,
                        float* __restrict__ loss_out) {
    const int wave = threadIdx.x >> 6, lane = threadIdx.x & 63;
    float s = 0.0f;
    for (int i = threadIdx.x; i < VQ_N / 4; i += 256) s += partials[i];
    #pragma unroll
    for (int off = 1; off < 64; off <<= 1) s += __shfl_xor(s, off, 64);
    __shared__ float ls[4];
    if (lane == 0) ls[wave] = s;
    __syncthreads();
    if (threadIdx.x == 0)
        *loss_out = (ls[0] + ls[1] + ls[2] + ls[3])
                    * (1.0f / ((float)VQ_N * (float)VQ_D));
}

// ---------------------------------------------------------------------------
// d_out: [out N*D | ind N | loss 1]. Dead-until-finalize regions host xb_sw
// (d_out[0,16MB)) and the queue (d_out[16MB,24MB)).
// ws: c2 16K | partials 128K | keys 256K | ctrl 64B | cbb_sw 2MB.
// 5 dispatches, no memsets, ONE GEMM pass.
// ---------------------------------------------------------------------------
extern "C" void kernel_launch(void* const* d_in, const int* in_sizes, int n_in,
                              void* d_out, int out_size, void* d_ws, size_t ws_size,
                              hipStream_t stream) {
    const float* x  = (const float*)d_in[0];
    const float* cb = (const float*)d_in[1];
    float* out      = (float*)d_out;
    float* ind_out  = out + (size_t)VQ_N * VQ_D;
    float* loss_out = ind_out + VQ_N;

    char* w = (char*)d_ws;
    float*              c2       = (float*)w;                         // 16 KB
    float*              partials = (float*)(w + 16384);               // 128 KB
    unsigned long long* keys     = (unsigned long long*)(w + 147456); // 256 KB
    unsigned int*       ctrl     = (unsigned int*)(w + 409600);       // 64 B
    unsigned int*       qcnt     = ctrl + 0;
    unsigned int*       overflow = ctrl + 1;
    short8*             cbb_sw   = (short8*)(w + 409664);             // 2 MB

    short8*       xb_sw = (short8*)d_out;                             // 16 MB
    unsigned int* queue = (unsigned int*)((char*)d_out + (16u << 20)); // 8 MB

    prep_all_kernel<<<2433, 256, 0, stream>>>(x, cb, xb_sw, cbb_sw, c2,
                                              keys, ctrl);

    sweep_kernel<<<VQ_N / 128, 512, 0, stream>>>(xb_sw, cbb_sw, c2,
                                                 qcnt, overflow, queue);

    qrerank_kernel<<<2048, 256, 0, stream>>>(x, cb, c2, qcnt, overflow, queue, keys);

    finalize_kernel<<<VQ_N / 4, 256, 0, stream>>>(x, cb, keys, out, ind_out,
                                                  partials);
    loss_reduce_kernel<<<1, 256, 0, stream>>>(partials, loss_out);
}

// Round 10
// 299.635 us; speedup vs baseline: 2.0870x; 1.1520x over previous
//
#include <hip/hip_runtime.h>
#include <hip/hip_bf16.h>

// N=32768 queries, D=256 dims, K=4096 codes (fp32 in/out).
#define VQ_N 32768
#define VQ_D 256
#define VQ_K 4096
#define BAND 16.0f                 // >= 2 * worst-case bf16 score error (~7.6)
#define QCAP (2u * 1024u * 1024u)  // global queue capacity (u32 entries)
#define BUFCAP 3072                // per-block LDS queue buffer (64-row block)

typedef __attribute__((ext_vector_type(8))) short short8;  // 8 bf16 (4 VGPRs)
typedef __attribute__((ext_vector_type(4))) float f32x4;   // MFMA C/D frag

// monotone float<->uint map (total order incl. negatives)
__device__ __forceinline__ unsigned fmap(float f) {
    unsigned b = __float_as_uint(f);
    return (b & 0x80000000u) ? ~b : (b | 0x80000000u);
}
__device__ __forceinline__ float fmapinv(unsigned u) {
    unsigned b = (u & 0x80000000u) ? (u & 0x7FFFFFFFu) : ~u;
    return __uint_as_float(b);
}

// async global->LDS: global src is PER-LANE, LDS dest is wave-uniform base,
// HW writes base + lane*16.
__device__ __forceinline__ void async16(const void* g, void* l) {
    __builtin_amdgcn_global_load_lds(
        (const __attribute__((address_space(1))) unsigned int*)g,
        (__attribute__((address_space(3))) unsigned int*)l, 16, 0, 0);
}

__device__ __forceinline__ short8 pack8(float4 a, float4 b) {
    union { __hip_bfloat16 h[8]; short8 s8; } u;
    u.h[0] = __float2bfloat16(a.x); u.h[1] = __float2bfloat16(a.y);
    u.h[2] = __float2bfloat16(a.z); u.h[3] = __float2bfloat16(a.w);
    u.h[4] = __float2bfloat16(b.x); u.h[5] = __float2bfloat16(b.y);
    u.h[6] = __float2bfloat16(b.z); u.h[7] = __float2bfloat16(b.w);
    return u.s8;
}

// ---------------------------------------------------------------------------
// prep_all: fused fp32->bf16 swizzled layouts + c2 + inits (unchanged).
//  blocks [0,2048):    xb_sw  — bf16 x, slot s of row holds k-quad q=s^(row&15)
//  blocks [2048,2304): cbb_sw — bf16 -2*cb, slot j=ks*4+sl holds
//                      kq=(sl-(code>>1))&3; plus c2 (fp32 norms)
//  blocks [2304,2432): keys init
//  block  2432:        qcnt/overflow init
// ---------------------------------------------------------------------------
__global__ __launch_bounds__(256)
void prep_all_kernel(const float* __restrict__ x, const float* __restrict__ cb,
                     short8* __restrict__ xb_sw, short8* __restrict__ cbb_sw,
                     float* __restrict__ c2,
                     unsigned long long* __restrict__ keys,
                     unsigned int* __restrict__ ctrl /*qcnt,ovf*/) {
    const int b = blockIdx.x, t = threadIdx.x;
    if (b < 2048) {                       // ---- xb_sw: 16 rows per block
        #pragma unroll
        for (int h = 0; h < 2; ++h) {
            const int u   = t + h * 256;            // 0..511 slot-units
            const int row = b * 16 + (u >> 5);
            const int s   = u & 31;
            const int q   = s ^ (row & 15);
            const float4 a = reinterpret_cast<const float4*>(x)[(size_t)row * 64 + q * 2];
            const float4 c = reinterpret_cast<const float4*>(x)[(size_t)row * 64 + q * 2 + 1];
            xb_sw[(size_t)row * 32 + s] = pack8(a, c);
        }
    } else if (b < 2304) {                // ---- cbb_sw + c2: 16 codes per block
        const int code = (b - 2048) * 16 + (t >> 4);
        float ss = 0.0f;
        #pragma unroll
        for (int h = 0; h < 2; ++h) {
            const int j  = (t & 15) * 2 + h;        // 0..31
            const int ks = j >> 2, sl = j & 3;
            const int kq = (sl - (code >> 1)) & 3;
            const int k  = ks * 32 + kq * 8;
            const float4 a = reinterpret_cast<const float4*>(cb)[(size_t)code * 64 + k / 4];
            const float4 c = reinterpret_cast<const float4*>(cb)[(size_t)code * 64 + k / 4 + 1];
            ss += a.x*a.x + a.y*a.y + a.z*a.z + a.w*a.w
                + c.x*c.x + c.y*c.y + c.z*c.z + c.w*c.w;
            const float4 na = make_float4(-2.f*a.x, -2.f*a.y, -2.f*a.z, -2.f*a.w);
            const float4 nc = make_float4(-2.f*c.x, -2.f*c.y, -2.f*c.z, -2.f*c.w);
            cbb_sw[(size_t)code * 32 + j] = pack8(na, nc);
        }
        #pragma unroll
        for (int off = 1; off < 16; off <<= 1) ss += __shfl_xor(ss, off, 64);
        if ((t & 15) == 0) c2[code] = ss;
    } else if (b < 2432) {                // ---- keys init
        keys[(b - 2304) * 256 + t] = ~0ull;
    } else {                              // ---- control words
        if (t < 8) ctrl[t] = 0u;
    }
}

// ---------------------------------------------------------------------------
// SINGLE-PASS A-resident MFMA sweep, 64-ROW blocks for 2 blocks/CU.
// Block = 64 rows x ALL 4096 codes (grid = 512 = 2 blocks/CU -> two
// INDEPENDENT barrier domains per CU: one block's MFMA covers the other's
// stage/drain stalls). A-tile (32KB, swizzled) staged ONCE; B double-buffered
// (16KB/step), 128 steps (16 ccts x 8 ks). 8 waves as 2x4 over 64x256:
// wave tile 32 rows x 64 codes, acc[2][4], 8 MFMA + 6 conflict-free
// ds_read_b128 per step. Per cct: fold running row-min, barrier, collect
// codes with s~ <= runmin + BAND (superset of two-pass set -> exact rerank
// unchanged). Queue flushed once at block end.
// ---------------------------------------------------------------------------
__global__ __launch_bounds__(512, 4)
void sweep_kernel(const short8* __restrict__ xb_sw,
                  const short8* __restrict__ cbb_sw,
                  const float* __restrict__ c2,
                  unsigned int* __restrict__ qcnt,
                  unsigned int* __restrict__ overflow,
                  unsigned int* __restrict__ queue) {
    __shared__ __attribute__((aligned(16))) char As[64 * 512];       // 32 KB
    __shared__ __attribute__((aligned(16))) char Bs[2][256 * 64];    // 2x16 KB
    __shared__ unsigned int rowmin_s[64];    // running row-min (fmap'd)
    __shared__ unsigned int qbuf[BUFCAP];    // 12 KB
    __shared__ int qn_s, qbase_s;

    const int t = threadIdx.x;
    const int lane = t & 63, wave = t >> 6;        // 8 waves
    const int wr = wave >> 2, wc = wave & 3;       // 2x4: 32-row x 64-code tile
    const int fr = lane & 15, kg = lane >> 4;
    const int rowbase = blockIdx.x * 64;

    if (t < 64) rowmin_s[t] = 0xFFFFFFFFu;
    if (t == 0) qn_s = 0;

    // ---- stage A once: wave w covers rows [w*8, w*8+8), linear 16B slots
    {
        const char* asrc = (const char*)xb_sw + (size_t)rowbase * 512 + wave * 4096
                           + lane * 16;
        char* adst = As + wave * 4096;
        #pragma unroll
        for (int i = 0; i < 4; ++i)
            async16(asrc + i * 1024, adst + i * 1024);
    }
    // ---- stage B step 0 (cct=0, ks=0) into buf 0
    #pragma unroll
    for (int i = 0; i < 2; ++i) {
        const int code = wave * 32 + i * 16 + (lane >> 2);
        async16((const char*)cbb_sw + (size_t)code * 512 + (lane & 3) * 16,
                Bs[0] + wave * 2048 + i * 1024);
    }
    __syncthreads();                               // drains A + B0

    f32x4 acc[2][4];
    #pragma unroll
    for (int m = 0; m < 2; ++m)
        #pragma unroll
        for (int n = 0; n < 4; ++n) acc[m][n] = (f32x4){0.f, 0.f, 0.f, 0.f};

    int cur = 0;
    for (int step = 0; step < 128; ++step) {       // 16 ccts x 8 ks
        if (step + 1 < 128) {
            const int ncct = (step + 1) >> 3, nks = (step + 1) & 7;
            #pragma unroll
            for (int i = 0; i < 2; ++i) {
                const int code = ncct * 256 + wave * 32 + i * 16 + (lane >> 2);
                async16((const char*)cbb_sw + (size_t)code * 512 + nks * 64
                            + (lane & 3) * 16,
                        Bs[cur ^ 1] + wave * 2048 + i * 1024);
            }
        }
        const int ks = step & 7;

        short8 af[2], bf[4];
        #pragma unroll
        for (int m = 0; m < 2; ++m) {
            const int row = wr * 32 + m * 16 + fr;
            const int s   = ((ks << 2) | kg) ^ fr;     // row&15 == fr
            af[m] = *reinterpret_cast<const short8*>(&As[row * 512 + (s << 4)]);
        }
        #pragma unroll
        for (int n = 0; n < 4; ++n) {
            const int c = wc * 64 + n * 16 + fr;
            const int s = (kg + (c >> 1)) & 3;
            bf[n] = *reinterpret_cast<const short8*>(&Bs[cur][c * 64 + (s << 4)]);
        }
        #pragma unroll
        for (int m = 0; m < 2; ++m)
            #pragma unroll
            for (int n = 0; n < 4; ++n)
                acc[m][n] = __builtin_amdgcn_mfma_f32_16x16x32_bf16(af[m], bf[n], acc[m][n], 0, 0, 0);

        __syncthreads();   // staged next-B drained; all reads of Bs[cur] done
        cur ^= 1;

        if (ks == 7) {     // ---- per-cct epilogue: min-update, then collect
            const int cct = step >> 3;
            float c2v[4];
            #pragma unroll
            for (int n = 0; n < 4; ++n)
                c2v[n] = c2[cct * 256 + wc * 64 + n * 16 + fr];

            // (1) fold this cct into the running row-min
            #pragma unroll
            for (int m = 0; m < 2; ++m) {
                #pragma unroll
                for (int r = 0; r < 4; ++r) {
                    float v = acc[m][0][r] + c2v[0];
                    #pragma unroll
                    for (int n = 1; n < 4; ++n) v = fminf(v, acc[m][n][r] + c2v[n]);
                    #pragma unroll
                    for (int off = 1; off < 16; off <<= 1)
                        v = fminf(v, __shfl_xor(v, off, 64));  // 16 fr-lanes/row
                    if (fr == 0)
                        atomicMin(&rowmin_s[wr * 32 + m * 16 + kg * 4 + r], fmap(v));
                }
            }
            __syncthreads();   // running min (incl. this cct) visible

            // (2) collect codes within BAND of the running min (superset)
            #pragma unroll
            for (int m = 0; m < 2; ++m) {
                #pragma unroll
                for (int r = 0; r < 4; ++r) {
                    const int lrow = wr * 32 + m * 16 + kg * 4 + r;
                    const float thr = fmapinv(rowmin_s[lrow]) + BAND;
                    #pragma unroll
                    for (int n = 0; n < 4; ++n) {
                        const float v = acc[m][n][r] + c2v[n];
                        if (v <= thr) {
                            const int code = cct * 256 + wc * 64 + n * 16 + fr;
                            const int pos = atomicAdd(&qn_s, 1);
                            if (pos < BUFCAP)
                                qbuf[pos] = ((unsigned)(rowbase + lrow) << 12) | (unsigned)code;
                        }
                    }
                }
            }
            #pragma unroll
            for (int m = 0; m < 2; ++m)
                #pragma unroll
                for (int n = 0; n < 4; ++n) acc[m][n] = (f32x4){0.f, 0.f, 0.f, 0.f};
        }
    }

    // ---- flush queue once per block
    __syncthreads();
    if (t == 0) {
        int n = qn_s;
        if (n > BUFCAP) { atomicOr(overflow, 1u); n = BUFCAP; }
        qbase_s = (int)atomicAdd(qcnt, (unsigned)n);
        qn_s = n;
    }
    __syncthreads();
    const unsigned base = (unsigned)qbase_s;
    for (int i = t; i < qn_s; i += 512) {
        const unsigned p = base + (unsigned)i;
        if (p < QCAP) queue[p] = qbuf[i];
    }
}

// ---------------------------------------------------------------------------
// queue rerank: one entry per 16-lane quarter-wave. Exact fp32 score,
// atomicMin on (fmap(score)<<32)|code -> lowest-index tie-break.
// Overflow tail (~never): full exact scan.
// ---------------------------------------------------------------------------
__global__ __launch_bounds__(256)
void qrerank_kernel(const float* __restrict__ x, const float* __restrict__ cb,
                    const float* __restrict__ c2,
                    const unsigned int* __restrict__ qcnt,
                    const unsigned int* __restrict__ overflow,
                    const unsigned int* __restrict__ queue,
                    unsigned long long* __restrict__ keys) {
    const int t = threadIdx.x;
    const int g  = t >> 4;               // 16 quarter-wave groups per block
    const int sl = t & 15;
    const unsigned raw = *qcnt;
    const unsigned total = raw > QCAP ? QCAP : raw;
    const unsigned stride = gridDim.x * 16;
    for (unsigned e = blockIdx.x * 16 + g; e < total; e += stride) {
        const unsigned ent = queue[e];
        const int row = (int)(ent >> 12);
        const int code = (int)(ent & 0xFFFu);
        float d = 0.0f;
        #pragma unroll
        for (int i = 0; i < 4; ++i) {
            const float4 xv = reinterpret_cast<const float4*>(x)[(size_t)row * 64 + i * 16 + sl];
            const float4 cv = reinterpret_cast<const float4*>(cb)[(size_t)code * 64 + i * 16 + sl];
            d += xv.x * cv.x + xv.y * cv.y + xv.z * cv.z + xv.w * cv.w;
        }
        #pragma unroll
        for (int off = 1; off < 16; off <<= 1) d += __shfl_xor(d, off, 64);
        const float s = fmaf(-2.0f, d, c2[code]);
        if (sl == 0)
            atomicMin(&keys[row],
                      ((unsigned long long)fmap(s) << 32) | (unsigned)code);
    }
    if (raw > QCAP || *overflow) {       // ~never: exact fallback, wave/row
        const int wave = t >> 6, lane = t & 63;
        for (int row = blockIdx.x * 4 + wave; row < VQ_N; row += gridDim.x * 4) {
            const float4 xv = reinterpret_cast<const float4*>(x)[(size_t)row * 64 + lane];
            float bv = 3.4e38f; int bk = 0;
            for (int k = 0; k < VQ_K; ++k) {
                const float4 cv = reinterpret_cast<const float4*>(cb)[(size_t)k * 64 + lane];
                float d = fmaf(xv.x, cv.x, fmaf(xv.y, cv.y, fmaf(xv.z, cv.z, xv.w * cv.w)));
                #pragma unroll
                for (int off = 1; off < 64; off <<= 1) d += __shfl_xor(d, off, 64);
                const float s = fmaf(-2.0f, d, c2[k]);
                if (s < bv) { bv = s; bk = k; }
            }
            if (lane == 0)
                atomicMin(&keys[row],
                          ((unsigned long long)fmap(bv) << 32) | (unsigned)bk);
        }
    }
}

// ---------------------------------------------------------------------------
// finalize: keys -> ind, gather, per-block loss partial via plain store.
// ---------------------------------------------------------------------------
__global__ __launch_bounds__(256)
void finalize_kernel(const float* __restrict__ x, const float* __restrict__ cb,
                     const unsigned long long* __restrict__ keys,
                     float* __restrict__ out, float* __restrict__ ind_out,
                     float* __restrict__ partials) {
    const int wave = threadIdx.x >> 6, lane = threadIdx.x & 63;
    const int row = blockIdx.x * 4 + wave;
    const int code = (int)(keys[row] & 0xFFFFFFFFull);
    const float4 qv = reinterpret_cast<const float4*>(cb)[(size_t)code * 64 + lane];
    const float4 xv = reinterpret_cast<const float4*>(x)[(size_t)row * 64 + lane];
    reinterpret_cast<float4*>(out)[(size_t)row * 64 + lane] = qv;
    if (lane == 0) ind_out[row] = (float)code;
    const float dx = qv.x - xv.x, dy = qv.y - xv.y, dz = qv.z - xv.z, dw = qv.w - xv.w;
    float s = dx * dx + dy * dy + dz * dz + dw * dw;
    #pragma unroll
    for (int off = 1; off < 64; off <<= 1) s += __shfl_xor(s, off, 64);
    __shared__ float ls[4];
    if (lane == 0) ls[wave] = s;
    __syncthreads();
    if (threadIdx.x == 0) partials[blockIdx.x] = ls[0] + ls[1] + ls[2] + ls[3];
}

// single small block: reduce 8192 partials, scale, write loss
__global__ __launch_bounds__(256)
void loss_reduce_kernel(const float* __restrict__ partials,
                        float* __restrict__ loss_out) {
    const int wave = threadIdx.x >> 6, lane = threadIdx.x & 63;
    float s = 0.0f;
    for (int i = threadIdx.x; i < VQ_N / 4; i += 256) s += partials[i];
    #pragma unroll
    for (int off = 1; off < 64; off <<= 1) s += __shfl_xor(s, off, 64);
    __shared__ float ls[4];
    if (lane == 0) ls[wave] = s;
    __syncthreads();
    if (threadIdx.x == 0)
        *loss_out = (ls[0] + ls[1] + ls[2] + ls[3])
                    * (1.0f / ((float)VQ_N * (float)VQ_D));
}

// ---------------------------------------------------------------------------
// d_out: [out N*D | ind N | loss 1]. Dead-until-finalize regions host xb_sw
// (d_out[0,16MB)) and the queue (d_out[16MB,24MB)).
// ws: c2 16K | partials 128K | keys 256K | ctrl 64B | cbb_sw 2MB.
// 5 dispatches, no memsets, ONE GEMM pass, 2 sweep blocks per CU.
// ---------------------------------------------------------------------------
extern "C" void kernel_launch(void* const* d_in, const int* in_sizes, int n_in,
                              void* d_out, int out_size, void* d_ws, size_t ws_size,
                              hipStream_t stream) {
    const float* x  = (const float*)d_in[0];
    const float* cb = (const float*)d_in[1];
    float* out      = (float*)d_out;
    float* ind_out  = out + (size_t)VQ_N * VQ_D;
    float* loss_out = ind_out + VQ_N;

    char* w = (char*)d_ws;
    float*              c2       = (float*)w;                         // 16 KB
    float*              partials = (float*)(w + 16384);               // 128 KB
    unsigned long long* keys     = (unsigned long long*)(w + 147456); // 256 KB
    unsigned int*       ctrl     = (unsigned int*)(w + 409600);       // 64 B
    unsigned int*       qcnt     = ctrl + 0;
    unsigned int*       overflow = ctrl + 1;
    short8*             cbb_sw   = (short8*)(w + 409664);             // 2 MB

    short8*       xb_sw = (short8*)d_out;                             // 16 MB
    unsigned int* queue = (unsigned int*)((char*)d_out + (16u << 20)); // 8 MB

    prep_all_kernel<<<2433, 256, 0, stream>>>(x, cb, xb_sw, cbb_sw, c2,
                                              keys, ctrl);

    sweep_kernel<<<VQ_N / 64, 512, 0, stream>>>(xb_sw, cbb_sw, c2,
                                                qcnt, overflow, queue);

    qrerank_kernel<<<2048, 256, 0, stream>>>(x, cb, c2, qcnt, overflow, queue, keys);

    finalize_kernel<<<VQ_N / 4, 256, 0, stream>>>(x, cb, keys, out, ind_out,
                                                  partials);
    loss_reduce_kernel<<<1, 256, 0, stream>>>(partials, loss_out);
}